// Round 3
// baseline (627.519 us; speedup 1.0000x reference)
//
#include <hip/hip_runtime.h>
#include <math.h>

#define HID 64
#define BN_EPS 1e-5f
#define NBMAX 256

typedef unsigned int uint;
typedef unsigned short ushort;

// ============ radix-bucketed CSR build ============

__global__ __launch_bounds__(256) void k_bucket_hist(const int* __restrict__ ei, int E, int NB,
                                                     int* __restrict__ bcnt_d, int* __restrict__ bcnt_s) {
    __shared__ int hd[NBMAX], hs[NBMAX];
    int t = threadIdx.x;
    if (t < NB) { hd[t] = 0; hs[t] = 0; }
    __syncthreads();
    for (int e = blockIdx.x * 256 + t; e < E; e += gridDim.x * 256) {
        int src = ei[e], dst = ei[E + e];
        atomicAdd(&hs[src >> 8], 1);
        atomicAdd(&hd[dst >> 8], 1);
    }
    __syncthreads();
    if (t < NB) {
        if (hd[t]) atomicAdd(&bcnt_d[t], hd[t]);
        if (hs[t]) atomicAdd(&bcnt_s[t], hs[t]);
    }
}

__global__ __launch_bounds__(256) void k_bucket_scan(const int* __restrict__ bcnt_d, const int* __restrict__ bcnt_s,
                                                     int NB, int N, int E,
                                                     int* __restrict__ bbase_d, int* __restrict__ cursor_d,
                                                     int* __restrict__ bbase_s, int* __restrict__ cursor_s,
                                                     int* __restrict__ rowptr) {
    __shared__ int sh[256];
    int t = threadIdx.x;
    int v = (t < NB) ? bcnt_d[t] : 0;
    sh[t] = v; __syncthreads();
    for (int s = 1; s < 256; s <<= 1) { int u = (t >= s) ? sh[t - s] : 0; __syncthreads(); sh[t] += u; __syncthreads(); }
    int excl = sh[t] - v;
    if (t <= NB) bbase_d[t] = excl;
    if (t < NB) cursor_d[t] = excl;
    if (t == 0) rowptr[N] = E;
    __syncthreads();
    v = (t < NB) ? bcnt_s[t] : 0;
    sh[t] = v; __syncthreads();
    for (int s = 1; s < 256; s <<= 1) { int u = (t >= s) ? sh[t - s] : 0; __syncthreads(); sh[t] += u; __syncthreads(); }
    excl = sh[t] - v;
    if (t <= NB) bbase_s[t] = excl;
    if (t < NB) cursor_s[t] = excl;
}

__global__ __launch_bounds__(256) void k_scatter(const int* __restrict__ ei, int E, int NB,
                                                 int* __restrict__ cursor_d, int* __restrict__ cursor_s,
                                                 unsigned long long* __restrict__ bedge, int* __restrict__ bsrc) {
    __shared__ int hd[NBMAX], hs[NBMAX], curd[NBMAX], curs[NBMAX];
    int t = threadIdx.x;
    int chunk = (E + gridDim.x - 1) / gridDim.x;
    int e0 = blockIdx.x * chunk;
    int e1 = min(e0 + chunk, E);
    if (t < NB) { hd[t] = 0; hs[t] = 0; }
    __syncthreads();
    for (int e = e0 + t; e < e1; e += 256) {
        int src = ei[e], dst = ei[E + e];
        atomicAdd(&hd[dst >> 8], 1);
        atomicAdd(&hs[src >> 8], 1);
    }
    __syncthreads();
    if (t < NB) {
        curd[t] = hd[t] ? atomicAdd(&cursor_d[t], hd[t]) : 0;
        curs[t] = hs[t] ? atomicAdd(&cursor_s[t], hs[t]) : 0;
    }
    __syncthreads();
    for (int e = e0 + t; e < e1; e += 256) {
        int src = ei[e], dst = ei[E + e];
        int pd = atomicAdd(&curd[dst >> 8], 1);
        bedge[pd] = ((unsigned long long)(uint)dst << 32) | (uint)src;
        int ps = atomicAdd(&curs[src >> 8], 1);
        bsrc[ps] = src;
    }
}

__global__ __launch_bounds__(256) void k_build_csr(const unsigned long long* __restrict__ bedge,
                                                   const int* __restrict__ bbase_d, int N,
                                                   int* __restrict__ rowptr, int* __restrict__ eidx) {
    __shared__ int h[256], off[256], cur[256];
    int t = threadIdx.x, b = blockIdx.x;
    int base = bbase_d[b], end = bbase_d[b + 1];
    h[t] = 0; __syncthreads();
    for (int p = base + t; p < end; p += 256)
        atomicAdd(&h[(int)(bedge[p] >> 32) & 255], 1);
    __syncthreads();
    off[t] = h[t]; __syncthreads();
    for (int s = 1; s < 256; s <<= 1) { int u = (t >= s) ? off[t - s] : 0; __syncthreads(); off[t] += u; __syncthreads(); }
    int excl = off[t] - h[t];
    int node = (b << 8) + t;
    if (node <= N) rowptr[node] = base + excl;
    cur[t] = excl; __syncthreads();
    for (int p = base + t; p < end; p += 256) {
        unsigned long long be = bedge[p];
        int bin = (int)(be >> 32) & 255;
        int pos = atomicAdd(&cur[bin], 1);
        eidx[base + pos] = (int)(uint)(be & 0xffffffffULL);
    }
}

__global__ __launch_bounds__(256) void k_outdeg(const int* __restrict__ bsrc, const int* __restrict__ bbase_s,
                                                int N, float* __restrict__ dis) {
    __shared__ int h[256];
    int t = threadIdx.x, b = blockIdx.x;
    int base = bbase_s[b], end = bbase_s[b + 1];
    h[t] = 0; __syncthreads();
    for (int p = base + t; p < end; p += 256) atomicAdd(&h[bsrc[p] & 255], 1);
    __syncthreads();
    int node = (b << 8) + t;
    if (node < N) dis[node] = rsqrtf((float)(h[t] + 1));
}

// ============ BN stats ============

template <int F>
__global__ __launch_bounds__(256) void k_stats(const float* __restrict__ X, int n,
                                               float* __restrict__ stats) {
    const int RPB = 256 / F;
    int f = threadIdx.x & (F - 1);
    int rsub = threadIdx.x / F;
    float s = 0.f, q = 0.f;
    for (int r = blockIdx.x * RPB + rsub; r < n; r += gridDim.x * RPB) {
        float v = X[(size_t)r * F + f];
        s += v; q += v * v;
    }
    __shared__ float shs[256], shq[256];
    shs[threadIdx.x] = s; shq[threadIdx.x] = q;
    __syncthreads();
    if (threadIdx.x < F) {
        #pragma unroll
        for (int k = 1; k < RPB; k++) { s += shs[threadIdx.x + k * F]; q += shq[threadIdx.x + k * F]; }
        atomicAdd(&stats[f], s);
        atomicAdd(&stats[F + f], q);
    }
}

// ============ fold BN into linear ============

template <int K>
__global__ void k_fold(const float* __restrict__ stats, const float* __restrict__ gamma,
                       const float* __restrict__ beta, const float* __restrict__ W,
                       const float* __restrict__ bias, float n_inv,
                       float* __restrict__ Wout, float* __restrict__ bout, int has_bias) {
    int o = blockIdx.x;
    int f = threadIdx.x;
    float mu = stats[f] * n_inv;
    float var = stats[K + f] * n_inv - mu * mu;
    float a = gamma[f] * rsqrtf(var + BN_EPS);
    float w = W[(size_t)f * HID + o];
    Wout[(size_t)f * HID + o] = a * w;
    float contrib = (beta[f] - mu * a) * w;
    __shared__ float sh[K];
    sh[f] = contrib;
    __syncthreads();
    #pragma unroll
    for (int off = K / 2; off > 0; off >>= 1) {
        if (f < off) sh[f] += sh[f + off];
        __syncthreads();
    }
    if (f == 0) bout[o] = sh[0] + (has_bias ? bias[o] : 0.f);
}

// ============ GEMM: 4 threads per row, 16 output cols each ============

__device__ inline uint bf16pk(float a, float b) {
    uint ua = __builtin_bit_cast(uint, a);
    ua += 0x7fff + ((ua >> 16) & 1);
    uint ub = __builtin_bit_cast(uint, b);
    ub += 0x7fff + ((ub >> 16) & 1);
    return (ua >> 16) | (ub & 0xffff0000u);
}

// out[n,64] = X[n,K] @ W[K,64] + b.  DIS: scale by dis[row], store bf16. RELU: relu, store f32.
template <int K, bool RELU, bool DIS>
__global__ __launch_bounds__(256) void k_gemm(const float* __restrict__ X, const float* __restrict__ W,
                                              const float* __restrict__ bias, const float* __restrict__ dis,
                                              void* __restrict__ out, int n) {
    int tid = blockIdx.x * 256 + threadIdx.x;
    int row = tid >> 2;             // 4 threads per row
    int c = (tid & 3) * 16;         // this thread's 16 output columns
    if (row >= n) return;
    float4 acc[4];
    const float4* b4 = (const float4*)(bias + c);
    #pragma unroll
    for (int j = 0; j < 4; j++) acc[j] = b4[j];
    const float* xrow = X + (size_t)row * K;
    #pragma unroll 1
    for (int kc = 0; kc < K; kc += 16) {
        float4 xr[4];
        const float4* xp = (const float4*)(xrow + kc);
        #pragma unroll
        for (int i = 0; i < 4; i++) xr[i] = xp[i];
        #pragma unroll
        for (int kk = 0; kk < 16; kk++) {
            float xv = ((const float*)xr)[kk];
            const float4* w4 = (const float4*)(W + (size_t)(kc + kk) * HID + c);
            #pragma unroll
            for (int j = 0; j < 4; j++) {
                float4 w = w4[j];
                acc[j].x = fmaf(xv, w.x, acc[j].x);
                acc[j].y = fmaf(xv, w.y, acc[j].y);
                acc[j].z = fmaf(xv, w.z, acc[j].z);
                acc[j].w = fmaf(xv, w.w, acc[j].w);
            }
        }
    }
    if constexpr (DIS) {
        float d = dis[row];
        uint4* o4 = (uint4*)((ushort*)out + (size_t)row * HID + c);
        #pragma unroll
        for (int h = 0; h < 2; h++) {
            float4 a = acc[2 * h], b = acc[2 * h + 1];
            uint4 pk;
            pk.x = bf16pk(a.x * d, a.y * d);
            pk.y = bf16pk(a.z * d, a.w * d);
            pk.z = bf16pk(b.x * d, b.y * d);
            pk.w = bf16pk(b.z * d, b.w * d);
            o4[h] = pk;
        }
    } else {
        float4* o4 = (float4*)((float*)out + (size_t)row * HID + c);
        #pragma unroll
        for (int j = 0; j < 4; j++) {
            float4 v = acc[j];
            if (RELU) { v.x = fmaxf(v.x, 0.f); v.y = fmaxf(v.y, 0.f); v.z = fmaxf(v.z, 0.f); v.w = fmaxf(v.w, 0.f); }
            o4[j] = v;
        }
    }
}

// ============ aggregation ============

__device__ inline float bfl(uint v) { return __builtin_bit_cast(float, v << 16); }
__device__ inline float bfh(uint v) { return __builtin_bit_cast(float, v & 0xffff0000u); }

__global__ __launch_bounds__(256) void k_agg(const ushort* __restrict__ s, const int* __restrict__ rowptr,
                                             const int* __restrict__ eidx, const float* __restrict__ dis,
                                             const float* __restrict__ bias, float* __restrict__ out, int n) {
    int wave = threadIdx.x >> 6;
    int lane = threadIdx.x & 63;
    int half = lane >> 5, li = lane & 31;
    int i = blockIdx.x * 8 + wave * 2 + half;
    if (i >= n) return;
    int f = li * 2;
    const uint* sp = (const uint*)s;
    uint v = sp[(size_t)i * 32 + li];
    float ax = bfl(v), ay = bfh(v);
    int q = rowptr[i], qe = rowptr[i + 1];
    for (; q + 4 <= qe; q += 4) {
        int j0 = eidx[q], j1 = eidx[q + 1], j2 = eidx[q + 2], j3 = eidx[q + 3];
        uint v0 = sp[(size_t)j0 * 32 + li];
        uint v1 = sp[(size_t)j1 * 32 + li];
        uint v2 = sp[(size_t)j2 * 32 + li];
        uint v3 = sp[(size_t)j3 * 32 + li];
        ax += (bfl(v0) + bfl(v1)) + (bfl(v2) + bfl(v3));
        ay += (bfh(v0) + bfh(v1)) + (bfh(v2) + bfh(v3));
    }
    for (; q < qe; ++q) {
        uint vv = sp[(size_t)eidx[q] * 32 + li];
        ax += bfl(vv); ay += bfh(vv);
    }
    float dd = dis[i];
    float2 r;
    r.x = fmaxf(fmaf(dd, ax, bias[f]), 0.f);
    r.y = fmaxf(fmaf(dd, ay, bias[f + 1]), 0.f);
    *(float2*)(out + (size_t)i * HID + f) = r;
}

// ============ global_add_pool ============

__global__ __launch_bounds__(256) void k_pool(const float* __restrict__ h, const int* __restrict__ batch,
                                              int n, float* __restrict__ out) {
    int g = blockIdx.x;
    int lo = 0, hi = n;
    while (lo < hi) { int mid = (lo + hi) >> 1; if (batch[mid] < g) lo = mid + 1; else hi = mid; }
    int start = lo;
    hi = n;
    while (lo < hi) { int mid = (lo + hi) >> 1; if (batch[mid] < g + 1) lo = mid + 1; else hi = mid; }
    int end = lo;
    int lane = threadIdx.x & 63;
    int rs = threadIdx.x >> 6;
    float acc = 0.f;
    for (int r = start + rs; r < end; r += 4) acc += h[(size_t)r * HID + lane];
    __shared__ float sh[256];
    sh[threadIdx.x] = acc;
    __syncthreads();
    if (threadIdx.x < 64) {
        acc = sh[threadIdx.x] + sh[64 + threadIdx.x] + sh[128 + threadIdx.x] + sh[192 + threadIdx.x];
        out[(size_t)g * HID + threadIdx.x] = acc;
    }
}

// ============ driver ============

extern "C" void kernel_launch(void* const* d_in, const int* in_sizes, int n_in,
                              void* d_out, int out_size, void* d_ws, size_t ws_size,
                              hipStream_t stream) {
    const float* x     = (const float*)d_in[0];
    const int*   ei    = (const int*)d_in[1];
    const int*   batch = (const int*)d_in[2];
    const float* bnfg  = (const float*)d_in[3];
    const float* bnfb  = (const float*)d_in[4];
    const float* Wfeat = (const float*)d_in[5];
    const float* bfeat = (const float*)d_in[6];
    const float* bng   = (const float*)d_in[7];
    const float* bnb   = (const float*)d_in[8];
    const float* Ws    = (const float*)d_in[9];
    const float* bs    = (const float*)d_in[10];
    float* out = (float*)d_out;

    const int N   = in_sizes[2];
    const int E   = in_sizes[1] / 2;
    const int FIN = in_sizes[0] / N;
    const int L   = in_sizes[9] / (HID * HID);
    const int G   = out_size / HID;
    const int NB  = (N + 255) >> 8;

    char* w = (char*)d_ws;
    auto alloc = [&](size_t bytes) { char* p = w; w += (bytes + 255) & ~(size_t)255; return p; };
    int*   bcnt_d = (int*)alloc(256 * 4);
    int*   bcnt_s = (int*)alloc(256 * 4);
    float* stats  = (float*)alloc(1024 * 4);
    size_t zero_bytes = (size_t)(w - (char*)d_ws);
    int*   bbase_d  = (int*)alloc(257 * 4);
    int*   cursor_d = (int*)alloc(256 * 4);
    int*   bbase_s  = (int*)alloc(257 * 4);
    int*   cursor_s = (int*)alloc(256 * 4);
    int*   rowptr   = (int*)alloc(((size_t)N + 1) * 4);
    int*   eidx     = (int*)alloc((size_t)E * 4);
    float* dis      = (float*)alloc((size_t)N * 4);
    float* Wf       = (float*)alloc((size_t)FIN * HID * 4);
    float* bf       = (float*)alloc(HID * 4);
    float* bufA     = (float*)alloc((size_t)N * HID * 4);
    ushort* bufB    = (ushort*)alloc((size_t)N * HID * 2);
    unsigned long long* bedge = (unsigned long long*)bufA;
    int* bsrc = (int*)bufB;

    hipMemsetAsync(d_ws, 0, zero_bytes, stream);

    int gR = (4 * N + 255) / 256;   // 4 threads per row

    // graph build
    k_bucket_hist<<<256, 256, 0, stream>>>(ei, E, NB, bcnt_d, bcnt_s);
    k_bucket_scan<<<1, 256, 0, stream>>>(bcnt_d, bcnt_s, NB, N, E,
                                         bbase_d, cursor_d, bbase_s, cursor_s, rowptr);
    k_scatter<<<256, 256, 0, stream>>>(ei, E, NB, cursor_d, cursor_s, bedge, bsrc);
    k_build_csr<<<NB, 256, 0, stream>>>(bedge, bbase_d, N, rowptr, eidx);
    k_outdeg<<<NB, 256, 0, stream>>>(bsrc, bbase_s, N, dis);

    // feature layer
    k_stats<128><<<256, 256, 0, stream>>>(x, N, stats);
    k_fold<128><<<HID, 128, 0, stream>>>(stats, bnfg, bnfb, Wfeat, bfeat, 1.f / (float)N, Wf, bf, 1);
    k_gemm<128, true, false><<<gR, 256, 0, stream>>>(x, Wf, bf, dis, bufA, N);

    // GCN layers
    for (int l = 0; l < L; ++l) {
        float* st = stats + 256 + 128 * l;
        k_stats<64><<<256, 256, 0, stream>>>(bufA, N, st);
        k_fold<64><<<HID, 64, 0, stream>>>(st, bng + (size_t)l * HID, bnb + (size_t)l * HID,
                                           Ws + (size_t)l * HID * HID, bf /*unused*/,
                                           1.f / (float)N, Wf, bf, 0);
        k_gemm<64, false, true><<<gR, 256, 0, stream>>>(bufA, Wf, bf, dis, (void*)bufB, N);
        k_agg<<<(N + 7) / 8, 256, 0, stream>>>(bufB, rowptr, eidx, dis, bs + (size_t)l * HID, bufA, N);
    }

    k_pool<<<G, 256, 0, stream>>>(bufA, batch, N, out);
}

// Round 4
// 493.285 us; speedup vs baseline: 1.2721x; 1.2721x over previous
//
#include <hip/hip_runtime.h>
#include <math.h>

#define HID 64
#define BN_EPS 1e-5f
#define NBMAX 256

typedef unsigned int uint;
typedef unsigned short ushort;

// ============ radix-bucketed CSR build ============

__global__ __launch_bounds__(256) void k_bucket_hist(const int* __restrict__ ei, int E, int NB,
                                                     int* __restrict__ bcnt_d, int* __restrict__ bcnt_s) {
    __shared__ int hd[NBMAX], hs[NBMAX];
    int t = threadIdx.x;
    if (t < NB) { hd[t] = 0; hs[t] = 0; }
    __syncthreads();
    for (int e = blockIdx.x * 256 + t; e < E; e += gridDim.x * 256) {
        int src = ei[e], dst = ei[E + e];
        atomicAdd(&hs[src >> 8], 1);
        atomicAdd(&hd[dst >> 8], 1);
    }
    __syncthreads();
    if (t < NB) {
        if (hd[t]) atomicAdd(&bcnt_d[t], hd[t]);
        if (hs[t]) atomicAdd(&bcnt_s[t], hs[t]);
    }
}

__global__ __launch_bounds__(256) void k_bucket_scan(const int* __restrict__ bcnt_d, const int* __restrict__ bcnt_s,
                                                     int NB, int N, int E,
                                                     int* __restrict__ bbase_d, int* __restrict__ cursor_d,
                                                     int* __restrict__ bbase_s, int* __restrict__ cursor_s,
                                                     int* __restrict__ rowptr) {
    __shared__ int sh[256];
    int t = threadIdx.x;
    int v = (t < NB) ? bcnt_d[t] : 0;
    sh[t] = v; __syncthreads();
    for (int s = 1; s < 256; s <<= 1) { int u = (t >= s) ? sh[t - s] : 0; __syncthreads(); sh[t] += u; __syncthreads(); }
    int excl = sh[t] - v;
    if (t <= NB) bbase_d[t] = excl;
    if (t < NB) cursor_d[t] = excl;
    if (t == 0) rowptr[N] = E;
    __syncthreads();
    v = (t < NB) ? bcnt_s[t] : 0;
    sh[t] = v; __syncthreads();
    for (int s = 1; s < 256; s <<= 1) { int u = (t >= s) ? sh[t - s] : 0; __syncthreads(); sh[t] += u; __syncthreads(); }
    excl = sh[t] - v;
    if (t <= NB) bbase_s[t] = excl;
    if (t < NB) cursor_s[t] = excl;
}

__global__ __launch_bounds__(256) void k_scatter(const int* __restrict__ ei, int E, int NB,
                                                 int* __restrict__ cursor_d, int* __restrict__ cursor_s,
                                                 unsigned long long* __restrict__ bedge, int* __restrict__ bsrc) {
    __shared__ int hd[NBMAX], hs[NBMAX], curd[NBMAX], curs[NBMAX];
    int t = threadIdx.x;
    int chunk = (E + gridDim.x - 1) / gridDim.x;
    int e0 = blockIdx.x * chunk;
    int e1 = min(e0 + chunk, E);
    if (t < NB) { hd[t] = 0; hs[t] = 0; }
    __syncthreads();
    for (int e = e0 + t; e < e1; e += 256) {
        int src = ei[e], dst = ei[E + e];
        atomicAdd(&hd[dst >> 8], 1);
        atomicAdd(&hs[src >> 8], 1);
    }
    __syncthreads();
    if (t < NB) {
        curd[t] = hd[t] ? atomicAdd(&cursor_d[t], hd[t]) : 0;
        curs[t] = hs[t] ? atomicAdd(&cursor_s[t], hs[t]) : 0;
    }
    __syncthreads();
    for (int e = e0 + t; e < e1; e += 256) {
        int src = ei[e], dst = ei[E + e];
        int pd = atomicAdd(&curd[dst >> 8], 1);
        bedge[pd] = ((unsigned long long)(uint)dst << 32) | (uint)src;
        int ps = atomicAdd(&curs[src >> 8], 1);
        bsrc[ps] = src;
    }
}

__global__ __launch_bounds__(256) void k_build_csr(const unsigned long long* __restrict__ bedge,
                                                   const int* __restrict__ bbase_d, int N,
                                                   int* __restrict__ rowptr, int* __restrict__ eidx) {
    __shared__ int h[256], off[256], cur[256];
    int t = threadIdx.x, b = blockIdx.x;
    int base = bbase_d[b], end = bbase_d[b + 1];
    h[t] = 0; __syncthreads();
    for (int p = base + t; p < end; p += 256)
        atomicAdd(&h[(int)(bedge[p] >> 32) & 255], 1);
    __syncthreads();
    off[t] = h[t]; __syncthreads();
    for (int s = 1; s < 256; s <<= 1) { int u = (t >= s) ? off[t - s] : 0; __syncthreads(); off[t] += u; __syncthreads(); }
    int excl = off[t] - h[t];
    int node = (b << 8) + t;
    if (node <= N) rowptr[node] = base + excl;
    cur[t] = excl; __syncthreads();
    for (int p = base + t; p < end; p += 256) {
        unsigned long long be = bedge[p];
        int bin = (int)(be >> 32) & 255;
        int pos = atomicAdd(&cur[bin], 1);
        eidx[base + pos] = (int)(uint)(be & 0xffffffffULL);
    }
}

__global__ __launch_bounds__(256) void k_outdeg(const int* __restrict__ bsrc, const int* __restrict__ bbase_s,
                                                int N, float* __restrict__ dis) {
    __shared__ int h[256];
    int t = threadIdx.x, b = blockIdx.x;
    int base = bbase_s[b], end = bbase_s[b + 1];
    h[t] = 0; __syncthreads();
    for (int p = base + t; p < end; p += 256) atomicAdd(&h[bsrc[p] & 255], 1);
    __syncthreads();
    int node = (b << 8) + t;
    if (node < N) dis[node] = rsqrtf((float)(h[t] + 1));
}

// ============ BN stats ============

template <int F>
__global__ __launch_bounds__(256) void k_stats(const float* __restrict__ X, int n,
                                               float* __restrict__ stats) {
    const int RPB = 256 / F;
    int f = threadIdx.x & (F - 1);
    int rsub = threadIdx.x / F;
    float s = 0.f, q = 0.f;
    for (int r = blockIdx.x * RPB + rsub; r < n; r += gridDim.x * RPB) {
        float v = X[(size_t)r * F + f];
        s += v; q += v * v;
    }
    __shared__ float shs[256], shq[256];
    shs[threadIdx.x] = s; shq[threadIdx.x] = q;
    __syncthreads();
    if (threadIdx.x < F) {
        #pragma unroll
        for (int k = 1; k < RPB; k++) { s += shs[threadIdx.x + k * F]; q += shq[threadIdx.x + k * F]; }
        atomicAdd(&stats[f], s);
        atomicAdd(&stats[F + f], q);
    }
}

// ============ fold BN into linear ============

template <int K>
__global__ void k_fold(const float* __restrict__ stats, const float* __restrict__ gamma,
                       const float* __restrict__ beta, const float* __restrict__ W,
                       const float* __restrict__ bias, float n_inv,
                       float* __restrict__ Wout, float* __restrict__ bout, int has_bias) {
    int o = blockIdx.x;
    int f = threadIdx.x;
    float mu = stats[f] * n_inv;
    float var = stats[K + f] * n_inv - mu * mu;
    float a = gamma[f] * rsqrtf(var + BN_EPS);
    float w = W[(size_t)f * HID + o];
    Wout[(size_t)f * HID + o] = a * w;
    float contrib = (beta[f] - mu * a) * w;
    __shared__ float sh[K];
    sh[f] = contrib;
    __syncthreads();
    #pragma unroll
    for (int off = K / 2; off > 0; off >>= 1) {
        if (f < off) sh[f] += sh[f + off];
        __syncthreads();
    }
    if (f == 0) bout[o] = sh[0] + (has_bias ? bias[o] : 0.f);
}

// ============ GEMM: wave-level K-split, W stays wave-uniform ============
// 256 threads = 4 waves. Wave w handles K-slice w (so W addresses are wave-uniform
// -> scalar/broadcast loads, the property R3 accidentally destroyed).
// 64 rows per block, lane = row. Partials reduced through padded LDS (stride 68
// floats -> quad-bank conflict-free b128), one barrier.

__device__ inline uint bf16pk(float a, float b) {
    uint ua = __builtin_bit_cast(uint, a);
    ua += 0x7fff + ((ua >> 16) & 1);
    uint ub = __builtin_bit_cast(uint, b);
    ub += 0x7fff + ((ub >> 16) & 1);
    return (ua >> 16) | (ub & 0xffff0000u);
}

template <int K, bool RELU, bool DIS>
__global__ __launch_bounds__(256) void k_gemm(const float* __restrict__ X, const float* __restrict__ W,
                                              const float* __restrict__ bias, const float* __restrict__ dis,
                                              void* __restrict__ out, int n) {
    constexpr int SPLIT = 4;
    constexpr int R = 64;            // rows per block (= lanes per wave)
    constexpr int KS = K / SPLIT;    // K per wave: 32 (K=128) or 16 (K=64)
    constexpr int RS = 68;           // padded LDS row stride (17*16B -> conflict-free)
    __shared__ float red[(SPLIT - 1) * R * RS];

    int t = threadIdx.x;
    int slice = t >> 6;              // wave id = K-slice (wave-uniform)
    int r = t & 63;                  // row within block
    int row = blockIdx.x * R + r;
    bool valid = row < n;

    float4 acc[16];
    #pragma unroll
    for (int j = 0; j < 16; j++) acc[j] = make_float4(0.f, 0.f, 0.f, 0.f);

    if (valid) {
        const float* xrow = X + (size_t)row * K + slice * KS;
        float4 xr[KS / 4];
        #pragma unroll
        for (int i = 0; i < KS / 4; i++) xr[i] = ((const float4*)xrow)[i];
        const float* wbase = W + (size_t)slice * KS * HID;   // wave-uniform
        #pragma unroll
        for (int kk = 0; kk < KS; kk++) {
            float xv = ((const float*)xr)[kk];
            const float4* w4 = (const float4*)(wbase + (size_t)kk * HID);  // wave-uniform
            #pragma unroll
            for (int j = 0; j < 16; j++) {
                float4 w = w4[j];
                acc[j].x = fmaf(xv, w.x, acc[j].x);
                acc[j].y = fmaf(xv, w.y, acc[j].y);
                acc[j].z = fmaf(xv, w.z, acc[j].z);
                acc[j].w = fmaf(xv, w.w, acc[j].w);
            }
        }
    }

    // waves 1..3 publish partials; wave 0 reduces + stores
    if (slice > 0) {
        float* dst = red + ((size_t)(slice - 1) * R + r) * RS;
        #pragma unroll
        for (int j = 0; j < 16; j++) *(float4*)(dst + 4 * j) = acc[j];
    }
    __syncthreads();
    if (slice != 0 || !valid) return;

    #pragma unroll
    for (int s = 0; s < SPLIT - 1; s++) {
        const float* src = red + ((size_t)s * R + r) * RS;
        #pragma unroll
        for (int j = 0; j < 16; j++) {
            float4 p = *(const float4*)(src + 4 * j);
            acc[j].x += p.x; acc[j].y += p.y; acc[j].z += p.z; acc[j].w += p.w;
        }
    }
    const float4* b4 = (const float4*)bias;
    if constexpr (DIS) {
        float d = dis[row];
        uint4* o4 = (uint4*)((ushort*)out + (size_t)row * HID);
        #pragma unroll
        for (int h = 0; h < 8; h++) {
            float4 a = acc[2 * h], b = acc[2 * h + 1];
            float4 ba = b4[2 * h], bb = b4[2 * h + 1];
            uint4 pk;
            pk.x = bf16pk((a.x + ba.x) * d, (a.y + ba.y) * d);
            pk.y = bf16pk((a.z + ba.z) * d, (a.w + ba.w) * d);
            pk.z = bf16pk((b.x + bb.x) * d, (b.y + bb.y) * d);
            pk.w = bf16pk((b.z + bb.z) * d, (b.w + bb.w) * d);
            o4[h] = pk;
        }
    } else {
        float4* o4 = (float4*)((float*)out + (size_t)row * HID);
        #pragma unroll
        for (int j = 0; j < 16; j++) {
            float4 v = acc[j], bb = b4[j];
            v.x += bb.x; v.y += bb.y; v.z += bb.z; v.w += bb.w;
            if (RELU) { v.x = fmaxf(v.x, 0.f); v.y = fmaxf(v.y, 0.f); v.z = fmaxf(v.z, 0.f); v.w = fmaxf(v.w, 0.f); }
            o4[j] = v;
        }
    }
}

// ============ aggregation ============

__device__ inline float bfl(uint v) { return __builtin_bit_cast(float, v << 16); }
__device__ inline float bfh(uint v) { return __builtin_bit_cast(float, v & 0xffff0000u); }

__global__ __launch_bounds__(256) void k_agg(const ushort* __restrict__ s, const int* __restrict__ rowptr,
                                             const int* __restrict__ eidx, const float* __restrict__ dis,
                                             const float* __restrict__ bias, float* __restrict__ out, int n) {
    int wave = threadIdx.x >> 6;
    int lane = threadIdx.x & 63;
    int half = lane >> 5, li = lane & 31;
    int i = blockIdx.x * 8 + wave * 2 + half;
    if (i >= n) return;
    int f = li * 2;
    const uint* sp = (const uint*)s;
    uint v = sp[(size_t)i * 32 + li];
    float ax = bfl(v), ay = bfh(v);
    int q = rowptr[i], qe = rowptr[i + 1];
    for (; q + 4 <= qe; q += 4) {
        int j0 = eidx[q], j1 = eidx[q + 1], j2 = eidx[q + 2], j3 = eidx[q + 3];
        uint v0 = sp[(size_t)j0 * 32 + li];
        uint v1 = sp[(size_t)j1 * 32 + li];
        uint v2 = sp[(size_t)j2 * 32 + li];
        uint v3 = sp[(size_t)j3 * 32 + li];
        ax += (bfl(v0) + bfl(v1)) + (bfl(v2) + bfl(v3));
        ay += (bfh(v0) + bfh(v1)) + (bfh(v2) + bfh(v3));
    }
    for (; q < qe; ++q) {
        uint vv = sp[(size_t)eidx[q] * 32 + li];
        ax += bfl(vv); ay += bfh(vv);
    }
    float dd = dis[i];
    float2 r;
    r.x = fmaxf(fmaf(dd, ax, bias[f]), 0.f);
    r.y = fmaxf(fmaf(dd, ay, bias[f + 1]), 0.f);
    *(float2*)(out + (size_t)i * HID + f) = r;
}

// ============ global_add_pool ============

__global__ __launch_bounds__(256) void k_pool(const float* __restrict__ h, const int* __restrict__ batch,
                                              int n, float* __restrict__ out) {
    int g = blockIdx.x;
    int lo = 0, hi = n;
    while (lo < hi) { int mid = (lo + hi) >> 1; if (batch[mid] < g) lo = mid + 1; else hi = mid; }
    int start = lo;
    hi = n;
    while (lo < hi) { int mid = (lo + hi) >> 1; if (batch[mid] < g + 1) lo = mid + 1; else hi = mid; }
    int end = lo;
    int lane = threadIdx.x & 63;
    int rs = threadIdx.x >> 6;
    float acc = 0.f;
    for (int r = start + rs; r < end; r += 4) acc += h[(size_t)r * HID + lane];
    __shared__ float sh[256];
    sh[threadIdx.x] = acc;
    __syncthreads();
    if (threadIdx.x < 64) {
        acc = sh[threadIdx.x] + sh[64 + threadIdx.x] + sh[128 + threadIdx.x] + sh[192 + threadIdx.x];
        out[(size_t)g * HID + threadIdx.x] = acc;
    }
}

// ============ driver ============

extern "C" void kernel_launch(void* const* d_in, const int* in_sizes, int n_in,
                              void* d_out, int out_size, void* d_ws, size_t ws_size,
                              hipStream_t stream) {
    const float* x     = (const float*)d_in[0];
    const int*   ei    = (const int*)d_in[1];
    const int*   batch = (const int*)d_in[2];
    const float* bnfg  = (const float*)d_in[3];
    const float* bnfb  = (const float*)d_in[4];
    const float* Wfeat = (const float*)d_in[5];
    const float* bfeat = (const float*)d_in[6];
    const float* bng   = (const float*)d_in[7];
    const float* bnb   = (const float*)d_in[8];
    const float* Ws    = (const float*)d_in[9];
    const float* bs    = (const float*)d_in[10];
    float* out = (float*)d_out;

    const int N   = in_sizes[2];
    const int E   = in_sizes[1] / 2;
    const int FIN = in_sizes[0] / N;
    const int L   = in_sizes[9] / (HID * HID);
    const int G   = out_size / HID;
    const int NB  = (N + 255) >> 8;

    char* w = (char*)d_ws;
    auto alloc = [&](size_t bytes) { char* p = w; w += (bytes + 255) & ~(size_t)255; return p; };
    int*   bcnt_d = (int*)alloc(256 * 4);
    int*   bcnt_s = (int*)alloc(256 * 4);
    float* stats  = (float*)alloc(1024 * 4);
    size_t zero_bytes = (size_t)(w - (char*)d_ws);
    int*   bbase_d  = (int*)alloc(257 * 4);
    int*   cursor_d = (int*)alloc(256 * 4);
    int*   bbase_s  = (int*)alloc(257 * 4);
    int*   cursor_s = (int*)alloc(256 * 4);
    int*   rowptr   = (int*)alloc(((size_t)N + 1) * 4);
    int*   eidx     = (int*)alloc((size_t)E * 4);
    float* dis      = (float*)alloc((size_t)N * 4);
    float* Wf       = (float*)alloc((size_t)FIN * HID * 4);
    float* bf       = (float*)alloc(HID * 4);
    float* bufA     = (float*)alloc((size_t)N * HID * 4);
    ushort* bufB    = (ushort*)alloc((size_t)N * HID * 2);
    unsigned long long* bedge = (unsigned long long*)bufA;
    int* bsrc = (int*)bufB;

    hipMemsetAsync(d_ws, 0, zero_bytes, stream);

    int gG = (N + 63) / 64;   // 64 rows per gemm block, 4 K-slice waves

    // graph build
    k_bucket_hist<<<256, 256, 0, stream>>>(ei, E, NB, bcnt_d, bcnt_s);
    k_bucket_scan<<<1, 256, 0, stream>>>(bcnt_d, bcnt_s, NB, N, E,
                                         bbase_d, cursor_d, bbase_s, cursor_s, rowptr);
    k_scatter<<<256, 256, 0, stream>>>(ei, E, NB, cursor_d, cursor_s, bedge, bsrc);
    k_build_csr<<<NB, 256, 0, stream>>>(bedge, bbase_d, N, rowptr, eidx);
    k_outdeg<<<NB, 256, 0, stream>>>(bsrc, bbase_s, N, dis);

    // feature layer
    k_stats<128><<<256, 256, 0, stream>>>(x, N, stats);
    k_fold<128><<<HID, 128, 0, stream>>>(stats, bnfg, bnfb, Wfeat, bfeat, 1.f / (float)N, Wf, bf, 1);
    k_gemm<128, true, false><<<gG, 256, 0, stream>>>(x, Wf, bf, dis, bufA, N);

    // GCN layers
    for (int l = 0; l < L; ++l) {
        float* st = stats + 256 + 128 * l;
        k_stats<64><<<256, 256, 0, stream>>>(bufA, N, st);
        k_fold<64><<<HID, 64, 0, stream>>>(st, bng + (size_t)l * HID, bnb + (size_t)l * HID,
                                           Ws + (size_t)l * HID * HID, bf /*unused*/,
                                           1.f / (float)N, Wf, bf, 0);
        k_gemm<64, false, true><<<gG, 256, 0, stream>>>(bufA, Wf, bf, dis, (void*)bufB, N);
        k_agg<<<(N + 7) / 8, 256, 0, stream>>>(bufB, rowptr, eidx, dis, bs + (size_t)l * HID, bufA, N);
    }

    k_pool<<<G, 256, 0, stream>>>(bufA, batch, N, out);
}